// Round 7
// baseline (44.539 us; speedup 1.0000x reference)
//
#include <hip/hip_runtime.h>
#include <math.h>

#define NB 4
#define NN 4096
#define QSCALE 0.1803368801f   // (1/sqrt(64)) * log2(e): scores in log2 domain

#define KS 8                   // key splits per q-tile
#define KPB 512                // keys per block
#define KPW 128                // keys per wave
#define NTW 8                  // 16-key tiles per wave
#define NG 4                   // q-groups (16 queries) per wave; q-tile = 64

typedef __bf16 bf16x8 __attribute__((ext_vector_type(8)));
typedef float f32x4 __attribute__((ext_vector_type(4)));
typedef float f32x2 __attribute__((ext_vector_type(2)));

union BF8 { unsigned short u[8]; bf16x8 v; uint4 q; };

static __device__ inline unsigned short f2bf(float f) {
    union { float f; unsigned u; } v; v.f = f;
    unsigned r = v.u + 0x7fffu + ((v.u >> 16) & 1u);   // RNE
    return (unsigned short)(r >> 16);
}

// ---------------------------------------------------------------------------
// Kernel 1 (MFMA prep, 32 positions/block, 512 blocks = 2/CU):
// waves 0,1 -> Q rows (bias+QSCALE), waves 2,3 -> K rows (bias).
// wve = Wo·Wv, cv = Wo·bv wave-parallel; VW = wve·x + cv.
// ---------------------------------------------------------------------------
__global__ __launch_bounds__(256) void prep_mfma(
    const float* __restrict__ x,
    const float* __restrict__ Wq, const float* __restrict__ bq,
    const float* __restrict__ Wk, const float* __restrict__ bk,
    const float* __restrict__ Wv, const float* __restrict__ bv,
    const float* __restrict__ Wo,
    unsigned short* __restrict__ Qb, unsigned short* __restrict__ Kb,
    float* __restrict__ VW)
{
    __shared__ float xt[64 * 33];                 // [c][n], n-pad 33
    __shared__ float wve_s[64];
    __shared__ unsigned short rows[4 * 16 * 72];  // per-wave 16x72 bf16

    const int blk = blockIdx.x;                   // NB*128
    const int b = blk >> 7;
    const int n0 = (blk & 127) << 5;
    const int tid = threadIdx.x;
    const int wid = tid >> 6, lane = tid & 63;
    const int lg = lane >> 4, ll = lane & 15;

    const float* xb = x + (size_t)b * 64 * NN;
    #pragma unroll
    for (int it = 0; it < 8; ++it) {
        int idx = it * 256 + tid;
        int c = idx >> 5, n = idx & 31;
        xt[c * 33 + n] = xb[(size_t)c * NN + n0 + n];
    }
    // wve[c] = sum_e Wo[e]*Wv[e*64+c], 4 lanes per c
    {
        int c = tid >> 2, part = tid & 3;
        float a = 0.f;
        #pragma unroll
        for (int j = 0; j < 16; ++j) {
            int e = part * 16 + j;
            a = fmaf(Wo[e], Wv[e * 64 + c], a);
        }
        a += __shfl_xor(a, 1);
        a += __shfl_xor(a, 2);
        if (part == 0) wve_s[c] = a;
    }
    // cv = Wo·bv via full-wave butterfly
    float cv;
    {
        float p = Wo[lane] * bv[lane];
        #pragma unroll
        for (int off = 1; off < 64; off <<= 1) p += __shfl_xor(p, off);
        cv = p;
    }
    __syncthreads();

    // VW: 8 lanes per position
    {
        int nrel = tid >> 3, part = tid & 7;
        float a = 0.f;
        #pragma unroll
        for (int j = 0; j < 8; ++j) {
            int c = part * 8 + j;
            a = fmaf(wve_s[c], xt[c * 33 + nrel], a);
        }
        a += __shfl_xor(a, 1);
        a += __shfl_xor(a, 2);
        a += __shfl_xor(a, 4);
        if (part == 0) VW[(size_t)b * NN + n0 + nrel] = a + cv;
    }

    // A fragments: rows n = (wid&1)*16 + ll
    const int nr = (wid & 1) * 16 + ll;
    BF8 a0, a1;
    #pragma unroll
    for (int j = 0; j < 8; ++j) {
        a0.v[j] = (__bf16)xt[(lg * 8 + j) * 33 + nr];
        a1.v[j] = (__bf16)xt[(32 + lg * 8 + j) * 33 + nr];
    }

    const float* W  = (wid < 2) ? Wq : Wk;
    const float* bs = (wid < 2) ? bq : bk;
    unsigned short* Out = (wid < 2) ? Qb : Kb;
    const float scale = (wid < 2) ? QSCALE : 1.f;
    unsigned short* myrows = rows + wid * (16 * 72);

    #pragma unroll
    for (int ct = 0; ct < 4; ++ct) {
        const float* wr = W + (ct * 16 + ll) * 64;
        float4 f0 = *(const float4*)(wr + lg * 8);
        float4 f1 = *(const float4*)(wr + lg * 8 + 4);
        float4 f2 = *(const float4*)(wr + 32 + lg * 8);
        float4 f3 = *(const float4*)(wr + 32 + lg * 8 + 4);
        BF8 w0, w1;
        w0.v[0] = (__bf16)f0.x; w0.v[1] = (__bf16)f0.y; w0.v[2] = (__bf16)f0.z; w0.v[3] = (__bf16)f0.w;
        w0.v[4] = (__bf16)f1.x; w0.v[5] = (__bf16)f1.y; w0.v[6] = (__bf16)f1.z; w0.v[7] = (__bf16)f1.w;
        w1.v[0] = (__bf16)f2.x; w1.v[1] = (__bf16)f2.y; w1.v[2] = (__bf16)f2.z; w1.v[3] = (__bf16)f2.w;
        w1.v[4] = (__bf16)f3.x; w1.v[5] = (__bf16)f3.y; w1.v[6] = (__bf16)f3.z; w1.v[7] = (__bf16)f3.w;
        f32x4 acc = {0.f, 0.f, 0.f, 0.f};
        acc = __builtin_amdgcn_mfma_f32_16x16x32_bf16(a0.v, w0.v, acc, 0, 0, 0);
        acc = __builtin_amdgcn_mfma_f32_16x16x32_bf16(a1.v, w1.v, acc, 0, 0, 0);
        float bias = bs[ct * 16 + ll];
        #pragma unroll
        for (int r = 0; r < 4; ++r)
            myrows[(lg * 4 + r) * 72 + ct * 16 + ll] = f2bf((acc[r] + bias) * scale);
    }
    // wave-local transpose readback
    {
        int n = lane >> 2, c16 = lane & 3;
        const uint4* sp = (const uint4*)&myrows[n * 72 + c16 * 16];
        uint4 v0 = sp[0], v1 = sp[1];
        uint4* dst = (uint4*)(Out + ((size_t)b * NN + n0 + (wid & 1) * 16 + n) * 64 + c16 * 16);
        dst[0] = v0; dst[1] = v1;
    }
}

// ---------------------------------------------------------------------------
// Kernel 2: MFMA attention. Q fragments in REGISTERS (no LDS in inner loop),
// NG=4 -> ~75 VGPR -> 6 waves/SIMD. Packed (Z,A) accumulate: one f32x2 fma
// per score (v_pk_fma_f32). No max-tracking (log2-domain scores, bounded).
// ---------------------------------------------------------------------------
__global__ __launch_bounds__(256, 6) void attn_mfma(
    const unsigned short* __restrict__ Qb, const unsigned short* __restrict__ Kb,
    const float* __restrict__ VW, float2* __restrict__ P2)
{
    __shared__ float vws[KPB];
    const int blk = blockIdx.x;                // ((b*64 + qt)*KS + ks)
    const int ks = blk & (KS - 1);
    const int t = blk >> 3;
    const int b = t >> 6;
    const int q0 = (t & 63) << 6;
    const int tid = threadIdx.x;
    const int wid = tid >> 6, lane = tid & 63;
    const int lg = lane >> 4, ll = lane & 15;

    for (int i = tid; i < KPB; i += 256)
        vws[i] = VW[(size_t)b * NN + ks * KPB + i];
    __syncthreads();

    bf16x8 qfa[NG], qfb[NG];
    #pragma unroll
    for (int g = 0; g < NG; ++g) {
        const unsigned short* qp = Qb + ((size_t)b * NN + q0 + g * 16 + ll) * 64 + lg * 8;
        qfa[g] = *(const bf16x8*)qp;
        qfb[g] = *(const bf16x8*)(qp + 32);
    }
    const unsigned short* kp =
        Kb + ((size_t)b * NN + ks * KPB + wid * KPW + ll) * 64 + lg * 8;

    f32x2 ZA[NG];
    #pragma unroll
    for (int g = 0; g < NG; ++g) ZA[g] = (f32x2){0.f, 0.f};

    #pragma unroll 2
    for (int kt = 0; kt < NTW; ++kt) {
        const bf16x8 ka0 = *(const bf16x8*)(kp + (size_t)kt * (16 * 64));
        const bf16x8 ka1 = *(const bf16x8*)(kp + (size_t)kt * (16 * 64) + 32);
        const float4 vv = *(const float4*)&vws[wid * KPW + kt * 16 + lg * 4];
        const f32x2 w0 = {1.f, vv.x}, w1 = {1.f, vv.y};
        const f32x2 w2 = {1.f, vv.z}, w3 = {1.f, vv.w};
        #pragma unroll
        for (int g = 0; g < NG; ++g) {
            f32x4 acc = {0.f, 0.f, 0.f, 0.f};
            acc = __builtin_amdgcn_mfma_f32_16x16x32_bf16(ka0, qfa[g], acc, 0, 0, 0);
            acc = __builtin_amdgcn_mfma_f32_16x16x32_bf16(ka1, qfb[g], acc, 0, 0, 0);
            float e0 = __builtin_amdgcn_exp2f(acc[0]);
            float e1 = __builtin_amdgcn_exp2f(acc[1]);
            float e2 = __builtin_amdgcn_exp2f(acc[2]);
            float e3 = __builtin_amdgcn_exp2f(acc[3]);
            ZA[g] = __builtin_elementwise_fma((f32x2){e0, e0}, w0, ZA[g]);
            ZA[g] = __builtin_elementwise_fma((f32x2){e1, e1}, w1, ZA[g]);
            ZA[g] = __builtin_elementwise_fma((f32x2){e2, e2}, w2, ZA[g]);
            ZA[g] = __builtin_elementwise_fma((f32x2){e3, e3}, w3, ZA[g]);
        }
    }

    float Zg[NG], Ag[NG];
    #pragma unroll
    for (int g = 0; g < NG; ++g) {
        float Z = ZA[g].x, A = ZA[g].y;
        Z += __shfl_xor(Z, 16); Z += __shfl_xor(Z, 32);
        A += __shfl_xor(A, 16); A += __shfl_xor(A, 32);
        Zg[g] = Z; Ag[g] = A;
    }
    const int r = ks * 4 + wid;                // 0..31
    float Zo = (lg == 0) ? Zg[0] : (lg == 1) ? Zg[1] : (lg == 2) ? Zg[2] : Zg[3];
    float Ao = (lg == 0) ? Ag[0] : (lg == 1) ? Ag[1] : (lg == 2) ? Ag[2] : Ag[3];
    P2[((size_t)r << 14) + ((size_t)b << 12) + q0 + lane] = make_float2(Zo, Ao);
}

// ---------------------------------------------------------------------------
// Kernel 3: sum 32 additive partials, sigmoid(A/Z + bo). 256 blocks x 64.
// ---------------------------------------------------------------------------
__global__ __launch_bounds__(64) void combine_kernel(
    const float2* __restrict__ P2, const float* __restrict__ bo,
    float* __restrict__ out)
{
    int i = blockIdx.x * 64 + threadIdx.x;     // NB*NN = 16384
    float Z = 0.f, A = 0.f;
    #pragma unroll
    for (int r = 0; r < 32; ++r) {
        float2 p = P2[((size_t)r << 14) + i];
        Z += p.x; A += p.y;
    }
    float y = A / Z + bo[0];
    out[i] = 1.f / (1.f + __expf(-y));
}

extern "C" void kernel_launch(void* const* d_in, const int* in_sizes, int n_in,
                              void* d_out, int out_size, void* d_ws, size_t ws_size,
                              hipStream_t stream)
{
    const float* x  = (const float*)d_in[0];
    const float* Wq = (const float*)d_in[1];
    const float* bq = (const float*)d_in[2];
    const float* Wk = (const float*)d_in[3];
    const float* bk = (const float*)d_in[4];
    const float* Wv = (const float*)d_in[5];
    const float* bv = (const float*)d_in[6];
    const float* Wo = (const float*)d_in[7];
    const float* bo = (const float*)d_in[8];
    float* out = (float*)d_out;

    unsigned short* Qb = (unsigned short*)d_ws;            // 2 MB
    unsigned short* Kb = Qb + (size_t)NB * NN * 64;        // 2 MB
    float* VW = (float*)(Kb + (size_t)NB * NN * 64);       // 64 KB
    float2* P2 = (float2*)(VW + (size_t)NB * NN);          // 4 MB

    prep_mfma<<<NB * 128, 256, 0, stream>>>(x, Wq, bq, Wk, bk, Wv, bv, Wo, Qb, Kb, VW);
    attn_mfma<<<NB * 64 * KS, 256, 0, stream>>>(Qb, Kb, VW, P2);
    combine_kernel<<<(NB * NN) / 64, 64, 0, stream>>>(P2, bo, out);
}